// Round 17
// baseline (77.232 us; speedup 1.0000x reference)
//
#include <hip/hip_runtime.h>
#include <hip/hip_bf16.h>

#define IMG    512
#define KSZ    11
#define HALO   5
#define STRIP  64          // cols per block (4 waves x 16)
#define PANEL  16          // rows per H panel / V step
#define FS     36          // per-field stride in u32 (32 pairs + 4 pad; ==0 mod 4)
#define CS     180         // per-col stride in u32 (5*FS; ==0 mod 4; 20cj bank spread)
#define WRSZ   (16 * CS)   // per-wave ring size in u32 (2880)

typedef short bf16x8 __attribute__((ext_vector_type(8)));
typedef float f32x4  __attribute__((ext_vector_type(4)));
union S8 { bf16x8 v; ushort u16[8]; uint u32[4]; };

__device__ __forceinline__ uint cvtpk(float lo, float hi) {
    uint r;
    asm("v_cvt_pk_bf16_f32 %0, %1, %2" : "=v"(r) : "v"(lo), "v"(hi));
    return r;
}
__device__ __forceinline__ float2 pk_mul(float2 a, float2 b) {
    float2 d;
    asm("v_pk_mul_f32 %0, %1, %2" : "=v"(d) : "v"(a), "v"(b));
    return d;
}
__device__ __forceinline__ ushort f2bf(float f) {   // prologue-only
    union { __hip_bfloat16 h; ushort u; } c;
    c.h = __float2bfloat16(f);
    return c.u;
}

// MFMA 16x16x32 bf16 layouts (validated end-to-end R12-R16):
//   A: row=lane&15, k=8*(lane>>4)+i   B: col=lane&15, k=8*(lane>>4)+i
//   D: col=lane&15, row=4*(lane>>4)+reg
// R17: TRANSPOSED per-wave ring [col][field][pair-row] so LDS ops vectorize:
//   H: 5 x ds_write_b64  (pairs p0,p0+1 contiguous; p0=(8t+2q+4)&31 EVEN
//      because ring row = abs+8 now)   [was 10 x b32]
//   V: 5 x ds_read_b128  (pairs (8s+4q)&31 +{0..3}, base mult-of-4) [was 20 x b32]
// With abs+8 shift, BOTH passes use the SAME Toeplitz g[k-cj-3]:
//   H: D[j]=sum_k data[win+k] g[k-j-3], win=cstrip+16wv-8 (unchanged)
//   V: B[k]=ring row 16s+k=abs 16s+k-8; d=k-j-3 -> abs=16s+j+d-5  OK
// Live span: V(t-2) oldest pair 8t-16, H(t) newest 8t+11 -> 28 < 32  OK
// V lag 2 + per-wave ring + no main-loop barriers (R15/R16 carried).

__global__ __launch_bounds__(256)
void dssim_mfma_kernel(const float* __restrict__ x,
                       const float* __restrict__ y,
                       const float* __restrict__ kern,
                       float* __restrict__ out)
{
    __shared__ float  sgf[16];
    __shared__ ushort gext[64];
    __shared__ __align__(16) uint Wring[4 * WRSZ];   // 46080 B
    __shared__ float  wsum[4];

    const int tid = threadIdx.x;
    const int l   = tid & 63;
    const int wv  = tid >> 6;
    const int q   = l >> 4;
    const int cj  = l & 15;
    const int wb  = wv * WRSZ;

    if (tid < KSZ) {
        float s = 0.f;
        #pragma unroll
        for (int j = 0; j < KSZ; ++j) s += kern[tid * KSZ + j];
        sgf[tid] = s;   // k2d rows sum to g (sum(g)==1)
    }
    // zero pad pair-rows 0..3 (ring rows 0..7 = abs -8..-1) of OWN ring:
    // 16 cols x 5 fields x 4 pairs = 320 u32
    for (int i = l; i < 320; i += 64) {
        const int col = i / 20, r = i % 20, f = r >> 2, p = r & 3;
        Wring[wb + col * CS + f * FS + p] = 0u;
    }
    __syncthreads();
    if (tid < 64) {
        const int d = tid - 18;    // slot 18+d holds g[d]
        gext[tid] = (d >= 0 && d < KSZ) ? f2bf(sgf[d]) : (ushort)0;
    }
    __syncthreads();               // last barrier before epilogue

    // Single Toeplitz frag for BOTH passes: g[k-cj-3] -> slot 15+k-cj.
    S8 tg;
    #pragma unroll
    for (int ii = 0; ii < 8; ++ii)
        tg.u16[ii] = gext[15 + q * 8 + ii - cj];

    const int plane  = blockIdx.z;
    const int half   = blockIdx.y;
    const int cstrip = blockIdx.x * STRIP;
    const int base   = plane * (IMG * IMG);

    const int  cb    = cstrip - 8 + 16 * wv + 8 * q;   // multiple of 8
    const bool colok = (cb >= 0) && (cb + 8 <= IMG);
    const float* xp  = x + base + cb;
    const float* yp  = y + base + cb;

    // half 0: iters t=0..17,  H for t<=16, V(s=t-2) for t>=2  (s=0..15)
    // half 1: iters t=15..33, H for t<=32, V(s=t-2) for t>=18 (s=16..31)
    const int t0   = half ? 15 : 0;
    const int t1   = half ? 33 : 17;
    const int hmax = half ? 32 : 16;
    const int vmin = half ? 18 : 2;

    const f32x4 z0 = {0.f, 0.f, 0.f, 0.f};
    const float C1 = 1e-4f, C2 = 9e-4f;
    float local = 0.f;
    int hb = (8 * t0) & 31;
    const int colbase = wb + cj * CS;   // this lane's ring column base

    // double-buffered load registers (2-deep pipeline)
    f32x4 xa0, xb0, ya0, yb0, xa1, xb1, ya1, yb1;

    auto load8 = [&](int t, f32x4& xa, f32x4& xb, f32x4& ya, f32x4& yb) {
        const int r = t * PANEL + cj;
        if (r < IMG && colok) {
            const float* px = xp + r * IMG;
            const float* py = yp + r * IMG;
            xa = *(const f32x4*)px;  xb = *(const f32x4*)(px + 4);
            ya = *(const f32x4*)py;  yb = *(const f32x4*)(py + 4);
        } else {
            xa = z0; xb = z0; ya = z0; yb = z0;
        }
    };

    auto step = [&](int t, f32x4& xa, f32x4& xb, f32x4& ya, f32x4& yb) {
        // ---- V(t-2) + SSIM first: ring data >=1 full iter old ----
        if (t >= vmin) {
            const int vbase = colbase + (((hb ^ 16) + 4 * q) & 31);
            f32x4 vf[5];
            #pragma unroll
            for (int f = 0; f < 5; ++f) {
                const uint4 bb = *(const uint4*)&Wring[vbase + f * FS];   // b128
                S8 b;
                b.u32[0] = bb.x; b.u32[1] = bb.y; b.u32[2] = bb.z; b.u32[3] = bb.w;
                vf[f] = __builtin_amdgcn_mfma_f32_16x16x32_bf16(tg.v, b.v, z0, 0, 0, 0);
            }
            #pragma unroll
            for (int r = 0; r < 4; ++r) {
                const float mx  = vf[0][r], my  = vf[1][r];
                const float exx = vf[2][r], eyy = vf[3][r], exy = vf[4][r];
                const float sxv = fmaf(-mx, mx, exx);
                const float syv = fmaf(-my, my, eyy);
                const float sxy = fmaf(-mx, my, exy);
                const float num = fmaf(2.f, mx * my, C1) * fmaf(2.f, sxy, C2);
                const float den = fmaf(mx, mx, fmaf(my, my, C1)) * (sxv + syv + C2);
                const float ssim = __fdividef(num, den + 1e-8f);
                local += (1.f - ssim) * 0.5f;
            }
        }

        if (t <= hmax) {
            // ---- build 5 bf16 A-frags (loads issued 2 iters ago) ----
            float2 x01 = {xa[0], xa[1]}, x23 = {xa[2], xa[3]};
            float2 x45 = {xb[0], xb[1]}, x67 = {xb[2], xb[3]};
            float2 y01 = {ya[0], ya[1]}, y23 = {ya[2], ya[3]};
            float2 y45 = {yb[0], yb[1]}, y67 = {yb[2], yb[3]};
            S8 fx, fy, fxx, fyy, fxy;
            #pragma unroll
            for (int w = 0; w < 4; ++w) {
                const float2 xv = (w == 0) ? x01 : (w == 1) ? x23 : (w == 2) ? x45 : x67;
                const float2 yv = (w == 0) ? y01 : (w == 1) ? y23 : (w == 2) ? y45 : y67;
                const float2 xxv = pk_mul(xv, xv);
                const float2 yyv = pk_mul(yv, yv);
                const float2 xyv = pk_mul(xv, yv);
                fx .u32[w] = cvtpk(xv.x,  xv.y);
                fy .u32[w] = cvtpk(yv.x,  yv.y);
                fxx.u32[w] = cvtpk(xxv.x, xxv.y);
                fyy.u32[w] = cvtpk(yyv.x, yyv.y);
                fxy.u32[w] = cvtpk(xyv.x, xyv.y);
            }

            // ---- refill this buffer for t+2 (regs just freed) ----
            if (t + 2 <= hmax) load8(t + 2, xa, xb, ya, yb);

            // ---- H(t): 5 MFMAs -> ring, one b64 write each ----
            const int hw = colbase + ((hb + 2 * q + 4) & 31);   // EVEN pair idx
            f32x4 d;
            uint2 w2;
            d = __builtin_amdgcn_mfma_f32_16x16x32_bf16(fx.v,  tg.v, z0, 0, 0, 0);
            w2.x = cvtpk(d[0], d[1]);  w2.y = cvtpk(d[2], d[3]);
            *(uint2*)&Wring[hw + 0 * FS] = w2;
            d = __builtin_amdgcn_mfma_f32_16x16x32_bf16(fy.v,  tg.v, z0, 0, 0, 0);
            w2.x = cvtpk(d[0], d[1]);  w2.y = cvtpk(d[2], d[3]);
            *(uint2*)&Wring[hw + 1 * FS] = w2;
            d = __builtin_amdgcn_mfma_f32_16x16x32_bf16(fxx.v, tg.v, z0, 0, 0, 0);
            w2.x = cvtpk(d[0], d[1]);  w2.y = cvtpk(d[2], d[3]);
            *(uint2*)&Wring[hw + 2 * FS] = w2;
            d = __builtin_amdgcn_mfma_f32_16x16x32_bf16(fyy.v, tg.v, z0, 0, 0, 0);
            w2.x = cvtpk(d[0], d[1]);  w2.y = cvtpk(d[2], d[3]);
            *(uint2*)&Wring[hw + 3 * FS] = w2;
            d = __builtin_amdgcn_mfma_f32_16x16x32_bf16(fxy.v, tg.v, z0, 0, 0, 0);
            w2.x = cvtpk(d[0], d[1]);  w2.y = cvtpk(d[2], d[3]);
            *(uint2*)&Wring[hw + 4 * FS] = w2;
        }

        hb = (hb + 8) & 31;
    };

    load8(t0,     xa0, xb0, ya0, yb0);
    load8(t0 + 1, xa1, xb1, ya1, yb1);

    for (int tt = t0; tt <= t1; tt += 2) {
        step(tt, xa0, xb0, ya0, yb0);
        if (tt + 1 <= t1) step(tt + 1, xa1, xb1, ya1, yb1);
    }

    // ---- block reduction, one atomic per block ----
    #pragma unroll
    for (int o = 32; o > 0; o >>= 1) local += __shfl_down(local, o, 64);
    if (l == 0) wsum[wv] = local;
    __syncthreads();
    if (tid == 0) {
        const float s = wsum[0] + wsum[1] + wsum[2] + wsum[3];
        atomicAdd(out, s * (1.f / 25165824.f));   // / (32*3*512*512)
    }
}

extern "C" void kernel_launch(void* const* d_in, const int* in_sizes, int n_in,
                              void* d_out, int out_size, void* d_ws, size_t ws_size,
                              hipStream_t stream)
{
    const float* x    = (const float*)d_in[0];
    const float* y    = (const float*)d_in[1];
    const float* kern = (const float*)d_in[2];
    float* out = (float*)d_out;

    hipMemsetAsync(out, 0, sizeof(float), stream);

    dim3 grid(IMG / STRIP, 2, 32 * 3);   // 8 strips x 2 halves x 96 planes
    dssim_mfma_kernel<<<grid, 256, 0, stream>>>(x, y, kern, out);
}

// Round 18
// 74.501 us; speedup vs baseline: 1.0367x; 1.0367x over previous
//
#include <hip/hip_runtime.h>
#include <hip/hip_bf16.h>

#define IMG    512
#define KSZ    11
#define HALO   5
#define STRIP  64          // cols per block (4 waves x 16)
#define PANEL  16          // rows per H panel / V step
#define FS     20          // per-field stride in u32 = 20 pairs (5 groups of 4)
#define CS     100         // per-col stride in u32 (5 fields * FS)
#define WRSZ   1600        // per-wave ring size in u32 (16 cols * CS)

typedef short bf16x8 __attribute__((ext_vector_type(8)));
typedef float f32x4  __attribute__((ext_vector_type(4)));
union S8 { bf16x8 v; ushort u16[8]; uint u32[4]; };

__device__ __forceinline__ uint cvtpk(float lo, float hi) {
    uint r;
    asm("v_cvt_pk_bf16_f32 %0, %1, %2" : "=v"(r) : "v"(lo), "v"(hi));
    return r;
}
__device__ __forceinline__ float2 pk_mul(float2 a, float2 b) {
    float2 d;
    asm("v_pk_mul_f32 %0, %1, %2" : "=v"(d) : "v"(a), "v"(b));
    return d;
}
__device__ __forceinline__ ushort f2bf(float f) {   // prologue-only
    union { __hip_bfloat16 h; ushort u; } c;
    c.h = __float2bfloat16(f);
    return c.u;
}

// MFMA 16x16x32 bf16 layouts (validated end-to-end R12-R17):
//   A: row=lane&15, k=8*(lane>>4)+i   B: col=lane&15, k=8*(lane>>4)+i
//   D: col=lane&15, row=4*(lane>>4)+reg
// R18: LAG-1 + 20-pair ring (5 groups x 4 pairs, mod-5 group arithmetic)
// to halve LDS -> 25.6KB -> 6 blocks/CU resident == 6 blocks/CU lifetime
// (zero tail, 24 waves/CU ceiling). Live span: V(t-1) reads pairs
// 8t-8..8t+7 (groups 2t-2..2t+1 mod 5), H(t) writes 8t+4..8t+11 (groups
// 2t+1, 2t+2 mod 5) -> H's 2nd group only clobbers data V(t-2) finished.
// Order: H(t) THEN V(t-1) (V consumes H(t)'s fresh rows; same-wave
// lgkmcnt orders ds_write->ds_read, proven R15).
// Ring row = abs+8; ONE Toeplitz g[k-cj-3] serves both passes (R17).
// H: b64 write at group hg=(2t+1+(q>>1))%5, offset 2*(q&1);
// V: b128 read at group vg=(2(t-1)+q)%5 -> always group-aligned.

__global__ __launch_bounds__(256)
void dssim_mfma_kernel(const float* __restrict__ x,
                       const float* __restrict__ y,
                       const float* __restrict__ kern,
                       float* __restrict__ out)
{
    __shared__ float  sgf[16];
    __shared__ ushort gext[64];
    __shared__ __align__(16) uint Wring[4 * WRSZ];   // 25600 B
    __shared__ float  wsum[4];

    const int tid = threadIdx.x;
    const int l   = tid & 63;
    const int wv  = tid >> 6;
    const int q   = l >> 4;
    const int cj  = l & 15;
    const int wb  = wv * WRSZ;

    if (tid < KSZ) {
        float s = 0.f;
        #pragma unroll
        for (int j = 0; j < KSZ; ++j) s += kern[tid * KSZ + j];
        sgf[tid] = s;   // k2d rows sum to g (sum(g)==1)
    }
    // zero group 0 (pairs 0..3 = ring rows 0..7 = abs -8..-1) of OWN ring
    for (int i = l; i < 320; i += 64) {
        const int col = i / 20, r = i % 20, f = r >> 2, p = r & 3;
        Wring[wb + col * CS + f * FS + p] = 0u;
    }
    __syncthreads();
    if (tid < 64) {
        const int d = tid - 18;    // slot 18+d holds g[d]
        gext[tid] = (d >= 0 && d < KSZ) ? f2bf(sgf[d]) : (ushort)0;
    }
    __syncthreads();               // last barrier before epilogue

    // Single Toeplitz frag for BOTH passes: g[k-cj-3] -> slot 15+k-cj.
    S8 tg;
    #pragma unroll
    for (int ii = 0; ii < 8; ++ii)
        tg.u16[ii] = gext[15 + q * 8 + ii - cj];

    const int plane  = blockIdx.z;
    const int half   = blockIdx.y;
    const int cstrip = blockIdx.x * STRIP;
    const int base   = plane * (IMG * IMG);

    const int  cb    = cstrip - 8 + 16 * wv + 8 * q;   // multiple of 8
    const bool colok = (cb >= 0) && (cb + 8 <= IMG);
    const float* xp  = x + base + cb;
    const float* yp  = y + base + cb;

    // half 0: t=0..16,  H every iter, V(s=t-1) for t>=1  (s=0..15)
    // half 1: t=15..32, H every iter, V(s=t-1) for t>=17 (s=16..31)
    const int t0   = half ? 15 : 0;
    const int t1   = half ? 32 : 16;
    const int vmin = half ? 17 : 1;

    const f32x4 z0 = {0.f, 0.f, 0.f, 0.f};
    const float C1 = 1e-4f, C2 = 9e-4f;
    float local = 0.f;
    const int colbase = wb + cj * CS;   // this lane's ring column base

    // mod-5 ring group counters (advance by 2 each iter)
    int hg = (2 * t0 + 1 + (q >> 1)) % 5;          // H write group
    int vg = (2 * t0 - 2 + q + 10) % 5;            // V read group (s=t-1)
    const int ho = 2 * (q & 1);                    // H write offset in group

    // double-buffered load registers (2-deep pipeline)
    f32x4 xa0, xb0, ya0, yb0, xa1, xb1, ya1, yb1;

    auto load8 = [&](int t, f32x4& xa, f32x4& xb, f32x4& ya, f32x4& yb) {
        const int r = t * PANEL + cj;
        if (r < IMG && colok) {
            const float* px = xp + r * IMG;
            const float* py = yp + r * IMG;
            xa = *(const f32x4*)px;  xb = *(const f32x4*)(px + 4);
            ya = *(const f32x4*)py;  yb = *(const f32x4*)(py + 4);
        } else {
            xa = z0; xb = z0; ya = z0; yb = z0;
        }
    };

    auto step = [&](int t, f32x4& xa, f32x4& xb, f32x4& ya, f32x4& yb) {
        // ---- build 5 bf16 A-frags (loads issued 2 iters ago) ----
        float2 x01 = {xa[0], xa[1]}, x23 = {xa[2], xa[3]};
        float2 x45 = {xb[0], xb[1]}, x67 = {xb[2], xb[3]};
        float2 y01 = {ya[0], ya[1]}, y23 = {ya[2], ya[3]};
        float2 y45 = {yb[0], yb[1]}, y67 = {yb[2], yb[3]};
        S8 fx, fy, fxx, fyy, fxy;
        #pragma unroll
        for (int w = 0; w < 4; ++w) {
            const float2 xv = (w == 0) ? x01 : (w == 1) ? x23 : (w == 2) ? x45 : x67;
            const float2 yv = (w == 0) ? y01 : (w == 1) ? y23 : (w == 2) ? y45 : y67;
            const float2 xxv = pk_mul(xv, xv);
            const float2 yyv = pk_mul(yv, yv);
            const float2 xyv = pk_mul(xv, yv);
            fx .u32[w] = cvtpk(xv.x,  xv.y);
            fy .u32[w] = cvtpk(yv.x,  yv.y);
            fxx.u32[w] = cvtpk(xxv.x, xxv.y);
            fyy.u32[w] = cvtpk(yyv.x, yyv.y);
            fxy.u32[w] = cvtpk(xyv.x, xyv.y);
        }

        // ---- refill this buffer for t+2 (regs just freed) ----
        if (t + 2 <= t1) load8(t + 2, xa, xb, ya, yb);

        // ---- H(t): 5 MFMAs -> ring, one b64 write each ----
        {
            const int hw = colbase + hg * 4 + ho;
            f32x4 d;
            uint2 w2;
            d = __builtin_amdgcn_mfma_f32_16x16x32_bf16(fx.v,  tg.v, z0, 0, 0, 0);
            w2.x = cvtpk(d[0], d[1]);  w2.y = cvtpk(d[2], d[3]);
            *(uint2*)&Wring[hw + 0 * FS] = w2;
            d = __builtin_amdgcn_mfma_f32_16x16x32_bf16(fy.v,  tg.v, z0, 0, 0, 0);
            w2.x = cvtpk(d[0], d[1]);  w2.y = cvtpk(d[2], d[3]);
            *(uint2*)&Wring[hw + 1 * FS] = w2;
            d = __builtin_amdgcn_mfma_f32_16x16x32_bf16(fxx.v, tg.v, z0, 0, 0, 0);
            w2.x = cvtpk(d[0], d[1]);  w2.y = cvtpk(d[2], d[3]);
            *(uint2*)&Wring[hw + 2 * FS] = w2;
            d = __builtin_amdgcn_mfma_f32_16x16x32_bf16(fyy.v, tg.v, z0, 0, 0, 0);
            w2.x = cvtpk(d[0], d[1]);  w2.y = cvtpk(d[2], d[3]);
            *(uint2*)&Wring[hw + 3 * FS] = w2;
            d = __builtin_amdgcn_mfma_f32_16x16x32_bf16(fxy.v, tg.v, z0, 0, 0, 0);
            w2.x = cvtpk(d[0], d[1]);  w2.y = cvtpk(d[2], d[3]);
            *(uint2*)&Wring[hw + 4 * FS] = w2;
        }

        // ---- V(t-1) + SSIM (reads H(t-2)..H(t); lgkmcnt orders) ----
        if (t >= vmin) {
            const int vr = colbase + vg * 4;
            f32x4 vf[5];
            #pragma unroll
            for (int f = 0; f < 5; ++f) {
                const uint4 bb = *(const uint4*)&Wring[vr + f * FS];   // b128
                S8 b;
                b.u32[0] = bb.x; b.u32[1] = bb.y; b.u32[2] = bb.z; b.u32[3] = bb.w;
                vf[f] = __builtin_amdgcn_mfma_f32_16x16x32_bf16(tg.v, b.v, z0, 0, 0, 0);
            }
            #pragma unroll
            for (int r = 0; r < 4; ++r) {
                const float mx  = vf[0][r], my  = vf[1][r];
                const float exx = vf[2][r], eyy = vf[3][r], exy = vf[4][r];
                const float sxv = fmaf(-mx, mx, exx);
                const float syv = fmaf(-my, my, eyy);
                const float sxy = fmaf(-mx, my, exy);
                const float num = fmaf(2.f, mx * my, C1) * fmaf(2.f, sxy, C2);
                const float den = fmaf(mx, mx, fmaf(my, my, C1)) * (sxv + syv + C2);
                const float ssim = __fdividef(num, den + 1e-8f);
                local += (1.f - ssim) * 0.5f;
            }
        }

        hg += 2;  if (hg >= 5) hg -= 5;
        vg += 2;  if (vg >= 5) vg -= 5;
    };

    load8(t0,     xa0, xb0, ya0, yb0);
    load8(t0 + 1, xa1, xb1, ya1, yb1);

    for (int tt = t0; tt <= t1; tt += 2) {
        step(tt, xa0, xb0, ya0, yb0);
        if (tt + 1 <= t1) step(tt + 1, xa1, xb1, ya1, yb1);
    }

    // ---- block reduction, one atomic per block ----
    #pragma unroll
    for (int o = 32; o > 0; o >>= 1) local += __shfl_down(local, o, 64);
    if (l == 0) wsum[wv] = local;
    __syncthreads();
    if (tid == 0) {
        const float s = wsum[0] + wsum[1] + wsum[2] + wsum[3];
        atomicAdd(out, s * (1.f / 25165824.f));   // / (32*3*512*512)
    }
}

extern "C" void kernel_launch(void* const* d_in, const int* in_sizes, int n_in,
                              void* d_out, int out_size, void* d_ws, size_t ws_size,
                              hipStream_t stream)
{
    const float* x    = (const float*)d_in[0];
    const float* y    = (const float*)d_in[1];
    const float* kern = (const float*)d_in[2];
    float* out = (float*)d_out;

    hipMemsetAsync(out, 0, sizeof(float), stream);

    dim3 grid(IMG / STRIP, 2, 32 * 3);   // 8 strips x 2 halves x 96 planes
    dssim_mfma_kernel<<<grid, 256, 0, stream>>>(x, y, kern, out);
}

// Round 19
// 74.036 us; speedup vs baseline: 1.0432x; 1.0063x over previous
//
#include <hip/hip_runtime.h>
#include <hip/hip_bf16.h>

#define IMG    512
#define KSZ    11
#define HALO   5
#define STRIP  64          // cols per block (4 waves x 16)
#define PANEL  16          // rows per H panel / V step
#define FS     20          // per-field stride in u32 = 20 pairs (5 groups of 4)
#define CS     100         // per-col stride in u32 (5 fields * FS)
#define WRSZ   1600        // per-wave ring size in u32 (16 cols * CS)

typedef short bf16x8 __attribute__((ext_vector_type(8)));
typedef float f32x4  __attribute__((ext_vector_type(4)));
union S8 { bf16x8 v; ushort u16[8]; uint u32[4]; };

__device__ __forceinline__ uint cvtpk(float lo, float hi) {
    uint r;
    asm("v_cvt_pk_bf16_f32 %0, %1, %2" : "=v"(r) : "v"(lo), "v"(hi));
    return r;
}
__device__ __forceinline__ float2 pk_mul(float2 a, float2 b) {
    float2 d;
    asm("v_pk_mul_f32 %0, %1, %2" : "=v"(d) : "v"(a), "v"(b));
    return d;
}
__device__ __forceinline__ ushort f2bf(float f) {   // prologue-only
    union { __hip_bfloat16 h; ushort u; } c;
    c.h = __float2bfloat16(f);
    return c.u;
}

// MFMA 16x16x32 bf16 layouts (validated end-to-end R12-R18):
//   A: row=lane&15, k=8*(lane>>4)+i   B: col=lane&15, k=8*(lane>>4)+i
//   D: col=lane&15, row=4*(lane>>4)+reg
// R19: 4-DEEP global prefetch (Little's law: R18 had ~1.6 loads in flight
// per wave -> iter time pinned at ~Lat/2; 4 bufs -> ~Lat/4). Ring, Toeplitz,
// lag-1, mod-5 groups, grid all byte-identical to R18:
//   20-pair ring (5 groups x 4 pairs), ring row = abs+8,
//   ONE Toeplitz g[k-cj-3] both passes,
//   H: b64 write group (2t+1+(q>>1))%5 offset 2(q&1); V: b128 group (2(t-1)+q)%5,
//   order H(t) then V(t-1), same-wave lgkmcnt orders ds ops (R15).

__global__ __launch_bounds__(256)
void dssim_mfma_kernel(const float* __restrict__ x,
                       const float* __restrict__ y,
                       const float* __restrict__ kern,
                       float* __restrict__ out)
{
    __shared__ float  sgf[16];
    __shared__ ushort gext[64];
    __shared__ __align__(16) uint Wring[4 * WRSZ];   // 25600 B
    __shared__ float  wsum[4];

    const int tid = threadIdx.x;
    const int l   = tid & 63;
    const int wv  = tid >> 6;
    const int q   = l >> 4;
    const int cj  = l & 15;
    const int wb  = wv * WRSZ;

    if (tid < KSZ) {
        float s = 0.f;
        #pragma unroll
        for (int j = 0; j < KSZ; ++j) s += kern[tid * KSZ + j];
        sgf[tid] = s;   // k2d rows sum to g (sum(g)==1)
    }
    // zero group 0 (pairs 0..3 = ring rows 0..7 = abs -8..-1) of OWN ring
    for (int i = l; i < 320; i += 64) {
        const int col = i / 20, r = i % 20, f = r >> 2, p = r & 3;
        Wring[wb + col * CS + f * FS + p] = 0u;
    }
    __syncthreads();
    if (tid < 64) {
        const int d = tid - 18;    // slot 18+d holds g[d]
        gext[tid] = (d >= 0 && d < KSZ) ? f2bf(sgf[d]) : (ushort)0;
    }
    __syncthreads();               // last barrier before epilogue

    // Single Toeplitz frag for BOTH passes: g[k-cj-3] -> slot 15+k-cj.
    S8 tg;
    #pragma unroll
    for (int ii = 0; ii < 8; ++ii)
        tg.u16[ii] = gext[15 + q * 8 + ii - cj];

    const int plane  = blockIdx.z;
    const int half   = blockIdx.y;
    const int cstrip = blockIdx.x * STRIP;
    const int base   = plane * (IMG * IMG);

    const int  cb    = cstrip - 8 + 16 * wv + 8 * q;   // multiple of 8
    const bool colok = (cb >= 0) && (cb + 8 <= IMG);
    const float* xp  = x + base + cb;
    const float* yp  = y + base + cb;

    // half 0: t=0..16,  H every iter, V(s=t-1) for t>=1  (s=0..15)
    // half 1: t=15..32, H every iter, V(s=t-1) for t>=17 (s=16..31)
    const int t0   = half ? 15 : 0;
    const int t1   = half ? 32 : 16;
    const int vmin = half ? 17 : 1;

    const f32x4 z0 = {0.f, 0.f, 0.f, 0.f};
    const float C1 = 1e-4f, C2 = 9e-4f;
    float local = 0.f;
    const int colbase = wb + cj * CS;   // this lane's ring column base

    // mod-5 ring group counters (advance by 2 each iter)
    int hg = (2 * t0 + 1 + (q >> 1)) % 5;          // H write group
    int vg = (2 * t0 - 2 + q + 10) % 5;            // V read group (s=t-1)
    const int ho = 2 * (q & 1);                    // H write offset in group

    // 4-deep rotating load buffers (R19: keep >=4 wave-loads in flight)
    f32x4 xa0, xb0, ya0, yb0, xa1, xb1, ya1, yb1;
    f32x4 xa2, xb2, ya2, yb2, xa3, xb3, ya3, yb3;

    auto load8 = [&](int t, f32x4& xa, f32x4& xb, f32x4& ya, f32x4& yb) {
        const int r = t * PANEL + cj;
        if (r < IMG && colok) {
            const float* px = xp + r * IMG;
            const float* py = yp + r * IMG;
            xa = *(const f32x4*)px;  xb = *(const f32x4*)(px + 4);
            ya = *(const f32x4*)py;  yb = *(const f32x4*)(py + 4);
        } else {
            xa = z0; xb = z0; ya = z0; yb = z0;
        }
    };

    auto step = [&](int t, f32x4& xa, f32x4& xb, f32x4& ya, f32x4& yb) {
        // ---- build 5 bf16 A-frags (loads issued 4 iters ago) ----
        float2 x01 = {xa[0], xa[1]}, x23 = {xa[2], xa[3]};
        float2 x45 = {xb[0], xb[1]}, x67 = {xb[2], xb[3]};
        float2 y01 = {ya[0], ya[1]}, y23 = {ya[2], ya[3]};
        float2 y45 = {yb[0], yb[1]}, y67 = {yb[2], yb[3]};
        S8 fx, fy, fxx, fyy, fxy;
        #pragma unroll
        for (int w = 0; w < 4; ++w) {
            const float2 xv = (w == 0) ? x01 : (w == 1) ? x23 : (w == 2) ? x45 : x67;
            const float2 yv = (w == 0) ? y01 : (w == 1) ? y23 : (w == 2) ? y45 : y67;
            const float2 xxv = pk_mul(xv, xv);
            const float2 yyv = pk_mul(yv, yv);
            const float2 xyv = pk_mul(xv, yv);
            fx .u32[w] = cvtpk(xv.x,  xv.y);
            fy .u32[w] = cvtpk(yv.x,  yv.y);
            fxx.u32[w] = cvtpk(xxv.x, xxv.y);
            fyy.u32[w] = cvtpk(yyv.x, yyv.y);
            fxy.u32[w] = cvtpk(xyv.x, xyv.y);
        }

        // ---- refill this buffer for t+4 (regs just freed) ----
        if (t + 4 <= t1) load8(t + 4, xa, xb, ya, yb);

        // ---- H(t): 5 MFMAs -> ring, one b64 write each ----
        {
            const int hw = colbase + hg * 4 + ho;
            f32x4 d;
            uint2 w2;
            d = __builtin_amdgcn_mfma_f32_16x16x32_bf16(fx.v,  tg.v, z0, 0, 0, 0);
            w2.x = cvtpk(d[0], d[1]);  w2.y = cvtpk(d[2], d[3]);
            *(uint2*)&Wring[hw + 0 * FS] = w2;
            d = __builtin_amdgcn_mfma_f32_16x16x32_bf16(fy.v,  tg.v, z0, 0, 0, 0);
            w2.x = cvtpk(d[0], d[1]);  w2.y = cvtpk(d[2], d[3]);
            *(uint2*)&Wring[hw + 1 * FS] = w2;
            d = __builtin_amdgcn_mfma_f32_16x16x32_bf16(fxx.v, tg.v, z0, 0, 0, 0);
            w2.x = cvtpk(d[0], d[1]);  w2.y = cvtpk(d[2], d[3]);
            *(uint2*)&Wring[hw + 2 * FS] = w2;
            d = __builtin_amdgcn_mfma_f32_16x16x32_bf16(fyy.v, tg.v, z0, 0, 0, 0);
            w2.x = cvtpk(d[0], d[1]);  w2.y = cvtpk(d[2], d[3]);
            *(uint2*)&Wring[hw + 3 * FS] = w2;
            d = __builtin_amdgcn_mfma_f32_16x16x32_bf16(fxy.v, tg.v, z0, 0, 0, 0);
            w2.x = cvtpk(d[0], d[1]);  w2.y = cvtpk(d[2], d[3]);
            *(uint2*)&Wring[hw + 4 * FS] = w2;
        }

        // ---- V(t-1) + SSIM (reads H(t-2)..H(t); lgkmcnt orders) ----
        if (t >= vmin) {
            const int vr = colbase + vg * 4;
            f32x4 vf[5];
            #pragma unroll
            for (int f = 0; f < 5; ++f) {
                const uint4 bb = *(const uint4*)&Wring[vr + f * FS];   // b128
                S8 b;
                b.u32[0] = bb.x; b.u32[1] = bb.y; b.u32[2] = bb.z; b.u32[3] = bb.w;
                vf[f] = __builtin_amdgcn_mfma_f32_16x16x32_bf16(tg.v, b.v, z0, 0, 0, 0);
            }
            #pragma unroll
            for (int r = 0; r < 4; ++r) {
                const float mx  = vf[0][r], my  = vf[1][r];
                const float exx = vf[2][r], eyy = vf[3][r], exy = vf[4][r];
                const float sxv = fmaf(-mx, mx, exx);
                const float syv = fmaf(-my, my, eyy);
                const float sxy = fmaf(-mx, my, exy);
                const float num = fmaf(2.f, mx * my, C1) * fmaf(2.f, sxy, C2);
                const float den = fmaf(mx, mx, fmaf(my, my, C1)) * (sxv + syv + C2);
                const float ssim = __fdividef(num, den + 1e-8f);
                local += (1.f - ssim) * 0.5f;
            }
        }

        hg += 2;  if (hg >= 5) hg -= 5;
        vg += 2;  if (vg >= 5) vg -= 5;
    };

    load8(t0,     xa0, xb0, ya0, yb0);
    load8(t0 + 1, xa1, xb1, ya1, yb1);
    load8(t0 + 2, xa2, xb2, ya2, yb2);
    load8(t0 + 3, xa3, xb3, ya3, yb3);

    for (int tt = t0; tt <= t1; tt += 4) {
        step(tt, xa0, xb0, ya0, yb0);
        if (tt + 1 <= t1) step(tt + 1, xa1, xb1, ya1, yb1);
        if (tt + 2 <= t1) step(tt + 2, xa2, xb2, ya2, yb2);
        if (tt + 3 <= t1) step(tt + 3, xa3, xb3, ya3, yb3);
    }

    // ---- block reduction, one atomic per block ----
    #pragma unroll
    for (int o = 32; o > 0; o >>= 1) local += __shfl_down(local, o, 64);
    if (l == 0) wsum[wv] = local;
    __syncthreads();
    if (tid == 0) {
        const float s = wsum[0] + wsum[1] + wsum[2] + wsum[3];
        atomicAdd(out, s * (1.f / 25165824.f));   // / (32*3*512*512)
    }
}

extern "C" void kernel_launch(void* const* d_in, const int* in_sizes, int n_in,
                              void* d_out, int out_size, void* d_ws, size_t ws_size,
                              hipStream_t stream)
{
    const float* x    = (const float*)d_in[0];
    const float* y    = (const float*)d_in[1];
    const float* kern = (const float*)d_in[2];
    float* out = (float*)d_out;

    hipMemsetAsync(out, 0, sizeof(float), stream);

    dim3 grid(IMG / STRIP, 2, 32 * 3);   // 8 strips x 2 halves x 96 planes
    dssim_mfma_kernel<<<grid, 256, 0, stream>>>(x, y, kern, out);
}